// Round 10
// baseline (994.959 us; speedup 1.0000x reference)
//
#include <hip/hip_runtime.h>

// ---------- types / helpers ----------
typedef unsigned short bf16u;
typedef __attribute__((ext_vector_type(8))) short bf16x8;   // MFMA A/B frag (4 VGPR)
typedef __attribute__((ext_vector_type(4))) float f32x4;    // MFMA C/D frag

__device__ __forceinline__ float bf2f(bf16u u) {
    return __uint_as_float(((unsigned)u) << 16);
}
__device__ __forceinline__ bf16u f2bf(float f) {
    unsigned u = __float_as_uint(f);
    unsigned r = (u + 0x7fffu + ((u >> 16) & 1u)) >> 16;
    return (bf16u)r;
}
__device__ __forceinline__ float sigmoidf_(float x) {
    return 1.0f / (1.0f + __expf(-x));
}

// direct global->LDS 16B copy: lane i of the wave lands at ldst + i*16B.
__device__ __forceinline__ void gload_lds16(const bf16u* g, bf16u* l) {
    __builtin_amdgcn_global_load_lds(
        (const __attribute__((address_space(1))) unsigned int*)(const void*)g,
        (__attribute__((address_space(3))) unsigned int*)(void*)l, 16, 0, 0);
}

// ---------- dtype detection (flag=1 -> raw inputs fp32, 0 -> bf16) ----------
__global__ void init_flag_kernel(int* flag) {
    if (threadIdx.x == 0 && blockIdx.x == 0) *flag = 0;
}
__global__ __launch_bounds__(256) void detect_kernel(
    const void* x, int nelem, int* flag)
{
    const int scan = nelem < (1 << 20) ? nelem : (1 << 20);
    const bf16u* p = (const bf16u*)x;
    int bad = 0;
    for (int j = blockIdx.x * 256 + threadIdx.x; j < scan; j += 65536) {
        unsigned u = p[j];
        if ((u & 0x7F80u) == 0x7F80u) bad = 1;
    }
    if (bad) atomicOr(flag, 1);
}

// ---------- convert raw (bf16/fp32 per flag) -> bf16 ----------
__global__ __launch_bounds__(256) void cvt_bf_kernel(
    const void* __restrict__ in, bf16u* __restrict__ out, int n,
    const int* __restrict__ flagp)
{
    const int f32 = *flagp;
    const int i = blockIdx.x * 256 + threadIdx.x;
    if (i >= n) return;
    if (f32) out[i] = f2bf(((const float*)in)[i]);
    else     out[i] = ((const bf16u*)in)[i];
}

// ---------- all weight transposes in one dispatch ----------
struct WTab {
    const void* w[11];
    bf16u* wt[11];
    int K[11];
    int N[11];
};
__global__ __launch_bounds__(256) void wtrans_all(
    WTab tab, const int* __restrict__ flagp)
{
    __shared__ float tile[32][33];
    const int id = blockIdx.z;
    const int K = tab.K[id], N = tab.N[id];
    const int n0 = blockIdx.x * 32, k0 = blockIdx.y * 32;
    if (n0 >= N || k0 >= K) return;
    const void* W = tab.w[id];
    bf16u* Wt = tab.wt[id];
    const int f32 = *flagp;
    const int tx = threadIdx.x & 31, ty = threadIdx.x >> 5;
    #pragma unroll
    for (int r = 0; r < 4; ++r) {
        const int k = ty + r * 8;
        float v;
        if (f32) v = ((const float*)W)[(size_t)(k0 + k) * N + n0 + tx];
        else     v = bf2f(((const bf16u*)W)[(size_t)(k0 + k) * N + n0 + tx]);
        tile[k][tx] = v;
    }
    __syncthreads();
    #pragma unroll
    for (int r = 0; r < 4; ++r) {
        const int n = ty + r * 8;
        Wt[(size_t)(n0 + n) * K + k0 + tx] = f2bf(tile[tx][n]);
    }
}

// ---------- V transpose: vb [b*1024+j][512] -> vt [b][h][64 d][1024 j] ----------
__global__ __launch_bounds__(256) void vtrans_kernel(
    const bf16u* __restrict__ vb, bf16u* __restrict__ vt)
{
    __shared__ bf16u tile[32][33];
    const int j0 = blockIdx.x * 32;
    const int h = blockIdx.y >> 1, dt = (blockIdx.y & 1) * 32;
    const int b = blockIdx.z;
    const int tx = threadIdx.x & 31, ty = threadIdx.x >> 5;
    #pragma unroll
    for (int r = 0; r < 4; ++r) {
        const int j = ty + r * 8;
        tile[j][tx] = vb[(size_t)(b * 1024 + j0 + j) * 512 + h * 64 + dt + tx];
    }
    __syncthreads();
    #pragma unroll
    for (int r = 0; r < 4; ++r) {
        const int d = ty + r * 8;
        vt[(size_t)((b * 8 + h) * 64 + dt + d) * 1024 + j0 + tx] = tile[tx][d];
    }
}

// ---------- qu/qv = q + bias_u/v (bf16) ----------
__global__ __launch_bounds__(256) void add_qbias_kernel(
    const bf16u* __restrict__ qb, const void* __restrict__ bu,
    const void* __restrict__ bv, bf16u* __restrict__ qu,
    bf16u* __restrict__ qv, const int* __restrict__ flagp)
{
    const int f32 = *flagp;
    const int idx = blockIdx.x * 256 + threadIdx.x;
    const int c = idx & 511;
    const float q = bf2f(qb[idx]);
    float ub, vbias;
    if (f32) { ub = ((const float*)bu)[c]; vbias = ((const float*)bv)[c]; }
    else     { ub = bf2f(((const bf16u*)bu)[c]); vbias = bf2f(((const bf16u*)bv)[c]); }
    qu[idx] = f2bf(q + ub);
    qv[idx] = f2bf(q + vbias);
}

// ---------- LayerNorm ----------
// IN_MODE: 0=fp32 ws, 1=raw (flag dtype), 2=bf16 ws.
// OUT_MODE: 0=bf16 ws, 1=raw d_out (flag dtype).
template <int D, int IN_MODE, int OUT_MODE, bool SILU, bool COPY>
__global__ __launch_bounds__(256) void ln_kernel(
    const void* __restrict__ in_, const void* __restrict__ gvec,
    const void* __restrict__ bvec, void* __restrict__ out_,
    float* __restrict__ copy_out, const int* __restrict__ flagp)
{
    constexpr int VPT = D / 256;
    const int f32 = *flagp;
    const int row = blockIdx.x;
    const int tid = threadIdx.x;
    const size_t base = (size_t)row * D;
    float x[VPT];
    if (IN_MODE == 2 || (IN_MODE == 1 && !f32)) {
        const bf16u* in = (const bf16u*)in_;
        #pragma unroll
        for (int i = 0; i < VPT; ++i) x[i] = bf2f(in[base + tid + i * 256]);
    } else {
        const float* in = (const float*)in_;
        #pragma unroll
        for (int i = 0; i < VPT; ++i) x[i] = in[base + tid + i * 256];
    }
    float s = 0.f, q = 0.f;
    #pragma unroll
    for (int i = 0; i < VPT; ++i) { s += x[i]; q += x[i] * x[i]; }
    __shared__ float red[10];
    #pragma unroll
    for (int off = 32; off; off >>= 1) {
        s += __shfl_down(s, off, 64);
        q += __shfl_down(q, off, 64);
    }
    const int lane = tid & 63, wv = tid >> 6;
    if (lane == 0) { red[wv] = s; red[4 + wv] = q; }
    __syncthreads();
    if (tid == 0) {
        float ts = red[0] + red[1] + red[2] + red[3];
        float tq = red[4] + red[5] + red[6] + red[7];
        float mean = ts / (float)D;
        float var = tq / (float)D - mean * mean;
        red[8] = mean;
        red[9] = rsqrtf(var + 1e-5f);
    }
    __syncthreads();
    const float mean = red[8], rstd = red[9];
    #pragma unroll
    for (int i = 0; i < VPT; ++i) {
        const int c = tid + i * 256;
        float gv, bv;
        if (f32) {
            gv = ((const float*)gvec)[c];
            bv = ((const float*)bvec)[c];
        } else {
            gv = bf2f(((const bf16u*)gvec)[c]);
            bv = bf2f(((const bf16u*)bvec)[c]);
        }
        float v = (x[i] - mean) * rstd * gv + bv;
        if (SILU) v *= sigmoidf_(v);
        if (OUT_MODE == 0) {
            ((bf16u*)out_)[base + c] = f2bf(v);
        } else {
            if (f32) ((float*)out_)[base + c] = v;
            else     ((bf16u*)out_)[base + c] = f2bf(v);
        }
        if (COPY) copy_out[base + c] = x[i];
    }
}

// ---------- MFMA GEMM: C = res + alpha * act(A @ Wt^T + bias) ----------
// A fragments loaded DIRECT to registers (depth-1 rotation, per-wave).
// B tile through LDS, 3-stage, barrier gates B only (vmcnt(6) steady).
// XCD swizzle (m-fast). Swapped-operand D layout -> vector epilogue.
template <int TM>
__global__ __launch_bounds__(256) void gemm_mfma(
    const bf16u* __restrict__ A, const bf16u* __restrict__ Wt,
    const void* __restrict__ bias, const float* __restrict__ res,
    void* __restrict__ C, int M, int N, int K, float alpha, int act,
    int outbf, const int* __restrict__ flagp)
{
    constexpr int BUFSZ = 128 * 32;   // B-only buffer, bf16 elems (8 KB)
    constexpr int MI = 4;
    constexpr int NJ = (TM == 128) ? 4 : 2;
    __shared__ bf16u sh[3 * BUFSZ];
    const int f32 = *flagp;
    const int tid = threadIdx.x;
    const int mtiles = M / TM;
    const int lid = blockIdx.y * gridDim.x + blockIdx.x;
    const int bm = (lid % mtiles) * TM;
    const int bn = (lid / mtiles) * 128;
    const int lane = tid & 63, wvid = tid >> 6;
    const int wm = (TM == 128) ? (wvid >> 1) * 64 : 0;
    const int wn = (TM == 128) ? (wvid & 1) * 64 : wvid * 32;
    const int kq = (lane >> 4) * 8, fr = lane & 15;

    f32x4 acc[MI][NJ];
    {
        f32x4 z = {0.f, 0.f, 0.f, 0.f};
        #pragma unroll
        for (int i = 0; i < MI; ++i)
            #pragma unroll
            for (int j = 0; j < NJ; ++j) acc[i][j] = z;
    }

    // per-wave A fragment source rows
    const bf16u* Arow[MI];
    #pragma unroll
    for (int i = 0; i < MI; ++i)
        Arow[i] = A + (size_t)(bm + wm + i * 16 + fr) * K + kq;

    #define STAGE_B(k0, bufp)                                                   \
    {                                                                           \
        bf16u* base_ = (bufp);                                                  \
        _Pragma("unroll")                                                       \
        for (int t = 0; t < 2; ++t) {                                           \
            const int cc = wvid * 128 + t * 64 + lane;                          \
            gload_lds16(Wt + (size_t)(bn + (cc >> 2)) * K + (k0) + (cc & 3) * 8,\
                        base_ + cc * 8);                                        \
        }                                                                       \
    }

    const int KT = K / 32;
    uint4 acur[MI], anext[MI];
    #pragma unroll
    for (int i = 0; i < MI; ++i) acur[i] = *(const uint4*)(Arow[i]);
    STAGE_B(0, sh);
    STAGE_B(32, sh + BUFSZ);
    int bufidx = 0;
    for (int kt = 0; kt < KT; ++kt) {
        if (kt + 1 < KT) {
            #pragma unroll
            for (int i = 0; i < MI; ++i)
                anext[i] = *(const uint4*)(Arow[i] + (size_t)(kt + 1) * 32);
        }
        if (kt + 2 < KT) {
            int nb = bufidx + 2; if (nb >= 3) nb -= 3;
            STAGE_B((kt + 2) * 32, sh + nb * BUFSZ);
        }
        if (kt + 1 < KT)
            asm volatile("s_waitcnt vmcnt(6)\ns_barrier" ::: "memory");
        else
            asm volatile("s_waitcnt vmcnt(0)\ns_barrier" ::: "memory");
        const bf16u* buf = sh + bufidx * BUFSZ;
        bf16x8 bfr[NJ];
        #pragma unroll
        for (int j = 0; j < NJ; ++j)
            bfr[j] = *(const bf16x8*)&buf[(wn + j * 16 + fr) * 32 + kq];
        #pragma unroll
        for (int i = 0; i < MI; ++i) {
            bf16x8 af = *(const bf16x8*)&acur[i];
            #pragma unroll
            for (int j = 0; j < NJ; ++j)
                acc[i][j] = __builtin_amdgcn_mfma_f32_16x16x32_bf16(
                    bfr[j], af, acc[i][j], 0, 0, 0);
        }
        #pragma unroll
        for (int i = 0; i < MI; ++i) acur[i] = anext[i];
        ++bufidx; if (bufidx == 3) bufidx = 0;
    }
    #undef STAGE_B

    // epilogue: D[n = quad*4+reg][m = lane&15] -> vector stores
    const int quad = lane >> 4, col = lane & 15;
    #pragma unroll
    for (int j = 0; j < NJ; ++j) {
        const int n0 = bn + wn + j * 16 + quad * 4;
        float4 bv4 = {0.f, 0.f, 0.f, 0.f};
        if (bias) {
            if (f32) bv4 = *(const float4*)((const float*)bias + n0);
            else {
                ushort4 bu = *(const ushort4*)((const bf16u*)bias + n0);
                bv4.x = bf2f(bu.x); bv4.y = bf2f(bu.y);
                bv4.z = bf2f(bu.z); bv4.w = bf2f(bu.w);
            }
        }
        #pragma unroll
        for (int i = 0; i < MI; ++i) {
            const int m = bm + wm + i * 16 + col;
            const size_t off = (size_t)m * N + n0;
            float v[4];
            #pragma unroll
            for (int r = 0; r < 4; ++r) {
                float t = acc[i][j][r] + ((const float*)&bv4)[r];
                if (act == 1) t *= sigmoidf_(t);
                v[r] = t * alpha;
            }
            if (res) {
                float4 r4 = *(const float4*)(res + off);
                v[0] += r4.x; v[1] += r4.y; v[2] += r4.z; v[3] += r4.w;
            }
            if (outbf) {
                ushort4 o;
                o.x = f2bf(v[0]); o.y = f2bf(v[1]);
                o.z = f2bf(v[2]); o.w = f2bf(v[3]);
                *(ushort4*)((bf16u*)C + off) = o;
            } else {
                float4 o = {v[0], v[1], v[2], v[3]};
                *(float4*)((float*)C + off) = o;
            }
        }
    }
}

// ---------- attention score MFMA (dbuf, 2 batches, swapped epilogue) ----------
// grid (8 jt, 8 it, 32): z: h=z&7, bb=(z>>3)&1, which=z>>4.
__global__ __launch_bounds__(256) void attn_score_mfma(
    const bf16u* __restrict__ qu, const bf16u* __restrict__ qv,
    const bf16u* __restrict__ kb, const bf16u* __restrict__ pb,
    bf16u* __restrict__ S, bf16u* __restrict__ BD)
{
    constexpr int BUFSZ = 8192;
    __shared__ bf16u sh[2 * BUFSZ];
    const int tid = threadIdx.x;
    const int z = blockIdx.z;
    const int h = z & 7, bb = (z >> 3) & 1, which = z >> 4;
    const bf16u* A = (which ? qv : qu) + (size_t)bb * 524288;
    const bf16u* B = which ? pb : (kb + (size_t)bb * 524288);
    bf16u* C = (which ? BD : S) + (size_t)(bb * 8 + h) * 1048576;
    const int hoff = h * 64;
    const int bm = blockIdx.y * 128, bn = blockIdx.x * 128;
    const int lane = tid & 63, wvid = tid >> 6;
    const int wm = (wvid >> 1) * 64, wn = (wvid & 1) * 64;
    const int kq = (lane >> 4) * 8, fr = lane & 15;

    f32x4 acc[4][4];
    {
        f32x4 zr = {0.f, 0.f, 0.f, 0.f};
        #pragma unroll
        for (int i = 0; i < 4; ++i)
            #pragma unroll
            for (int j = 0; j < 4; ++j) acc[i][j] = zr;
    }

    #define STAGE_S(k0, bsel)                                                   \
    {                                                                           \
        bf16u* base_ = sh + (bsel) * BUFSZ;                                     \
        _Pragma("unroll")                                                       \
        for (int t = 0; t < 4; ++t) {                                           \
            const int cc = wvid * 256 + t * 64 + lane;                          \
            const bf16u* src_;                                                  \
            if (cc < 512)                                                       \
                src_ = A + (size_t)(bm + (cc >> 2)) * 512 + hoff + (k0) + (cc & 3) * 8; \
            else {                                                              \
                const int cb_ = cc - 512;                                       \
                src_ = B + (size_t)(bn + (cb_ >> 2)) * 512 + hoff + (k0) + (cb_ & 3) * 8; \
            }                                                                   \
            gload_lds16(src_, base_ + (wvid * 256 + t * 64) * 8);               \
        }                                                                       \
    }

    STAGE_S(0, 0);
    #pragma unroll
    for (int kt = 0; kt < 2; ++kt) {
        __syncthreads();
        if (kt == 0) STAGE_S(32, 1);
        const bf16u* buf = sh + (kt & 1) * BUFSZ;
        bf16x8 af[4], bfr[4];
        #pragma unroll
        for (int i = 0; i < 4; ++i)
            af[i] = *(const bf16x8*)&buf[(wm + i * 16 + fr) * 32 + kq];
        #pragma unroll
        for (int j = 0; j < 4; ++j)
            bfr[j] = *(const bf16x8*)&buf[4096 + (wn + j * 16 + fr) * 32 + kq];
        #pragma unroll
        for (int i = 0; i < 4; ++i)
            #pragma unroll
            for (int j = 0; j < 4; ++j)
                acc[i][j] = __builtin_amdgcn_mfma_f32_16x16x32_bf16(
                    bfr[j], af[i], acc[i][j], 0, 0, 0);
    }
    #undef STAGE_S

    const int quad = lane >> 4, col = lane & 15;
    #pragma unroll
    for (int j = 0; j < 4; ++j) {
        const int n0 = bn + wn + j * 16 + quad * 4;
        #pragma unroll
        for (int i = 0; i < 4; ++i) {
            const int m = bm + wm + i * 16 + col;
            ushort4 o;
            o.x = f2bf(acc[i][j][0] * 0.125f);
            o.y = f2bf(acc[i][j][1] * 0.125f);
            o.z = f2bf(acc[i][j][2] * 0.125f);
            o.w = f2bf(acc[i][j][3] * 0.125f);
            *(ushort4*)(C + (size_t)m * 1024 + n0) = o;
        }
    }
}

// ---------- softmax with rel-shift gather (bf16 S/BD, probs in-place, 2 batches) ----------
__global__ __launch_bounds__(256) void attn_softmax_kernel(
    bf16u* __restrict__ S, const bf16u* __restrict__ BD)
{
    const int i = blockIdx.x, h = blockIdx.y, bb = blockIdx.z;
    const int tid = threadIdx.x;
    const size_t hb = (size_t)(bb * 8 + h) * 1048576;
    bf16u* srow = S + hb + (size_t)i * 1024;
    const bf16u* bd0 = BD + hb + (size_t)i * 1024;
    const bf16u* bd1 = bd0 + 1024;
    float v[4];
    #pragma unroll
    for (int k = 0; k < 4; ++k) {
        const int j = tid + k * 256;
        float bd;
        if (j <= i)          bd = bf2f(bd0[1023 - i + j]);
        else if (j == i + 1) bd = 0.f;
        else                 bd = bf2f(bd1[j - i - 2]);
        v[k] = bf2f(srow[j]) + bd;
    }
    __shared__ float red[6];
    float m = fmaxf(fmaxf(v[0], v[1]), fmaxf(v[2], v[3]));
    #pragma unroll
    for (int off = 32; off; off >>= 1) m = fmaxf(m, __shfl_down(m, off, 64));
    const int lane = tid & 63, w = tid >> 6;
    if (lane == 0) red[w] = m;
    __syncthreads();
    if (tid == 0) red[4] = fmaxf(fmaxf(red[0], red[1]), fmaxf(red[2], red[3]));
    __syncthreads();
    m = red[4];
    float e[4], l = 0.f;
    #pragma unroll
    for (int k = 0; k < 4; ++k) { e[k] = __expf(v[k] - m); l += e[k]; }
    #pragma unroll
    for (int off = 32; off; off >>= 1) l += __shfl_down(l, off, 64);
    if (lane == 0) red[w] = l;
    __syncthreads();
    if (tid == 0) red[5] = red[0] + red[1] + red[2] + red[3];
    __syncthreads();
    const float inv = 1.0f / red[5];
    #pragma unroll
    for (int k = 0; k < 4; ++k) srow[tid + k * 256] = f2bf(e[k] * inv);
}

// ---------- attention PV MFMA (3-stage pipeline, 2 batches, swapped epilogue) ----------
// grid (16 i-tiles, 8 h, 2 bb). Tile M=64 i x N=64 d, K=1024 j.
__global__ __launch_bounds__(256) void attn_pv_mfma(
    const bf16u* __restrict__ P, const bf16u* __restrict__ Vt,
    bf16u* __restrict__ O)
{
    constexpr int BUFSZ = 4096;
    __shared__ bf16u sh[3 * BUFSZ];
    const int tid = threadIdx.x;
    const int h = blockIdx.y, bb = blockIdx.z;
    const int bm = blockIdx.x * 64;
    const int hoff = h * 64;
    const bf16u* Ph = P + (size_t)(bb * 8 + h) * 1048576;
    const bf16u* Vh = Vt + (size_t)bb * 524288 + (size_t)h * 65536;
    bf16u* Ob = O + (size_t)bb * 524288;
    const int lane = tid & 63, wvid = tid >> 6;
    const int wm = wvid * 16;
    const int kq = (lane >> 4) * 8, fr = lane & 15;

    f32x4 acc[4];
    {
        f32x4 z = {0.f, 0.f, 0.f, 0.f};
        #pragma unroll
        for (int j = 0; j < 4; ++j) acc[j] = z;
    }

    #define STAGE_P(k0, bufp)                                                   \
    {                                                                           \
        bf16u* base_ = (bufp);                                                  \
        _Pragma("unroll")                                                       \
        for (int t = 0; t < 2; ++t) {                                           \
            const int cc = wvid * 128 + t * 64 + lane;                          \
            const bf16u* src_;                                                  \
            if (cc < 256)                                                       \
                src_ = Ph + (size_t)(bm + (cc >> 2)) * 1024 + (k0) + (cc & 3) * 8; \
            else {                                                              \
                const int cb_ = cc - 256;                                       \
                src_ = Vh + (size_t)(cb_ >> 2) * 1024 + (k0) + (cb_ & 3) * 8;   \
            }                                                                   \
            gload_lds16(src_, base_ + (wvid * 128 + t * 64) * 8);               \
        }                                                                       \
    }

    STAGE_P(0, sh);
    STAGE_P(32, sh + BUFSZ);
    int bufidx = 0;
    for (int kt = 0; kt < 32; ++kt) {
        if (kt + 1 < 32)
            asm volatile("s_waitcnt vmcnt(2)\ns_barrier" ::: "memory");
        else
            asm volatile("s_waitcnt vmcnt(0)\ns_barrier" ::: "memory");
        if (kt + 2 < 32) {
            int nb = bufidx + 2; if (nb >= 3) nb -= 3;
            STAGE_P((kt + 2) * 32, sh + nb * BUFSZ);
        }
        const bf16u* buf = sh + bufidx * BUFSZ;
        bf16x8 af = *(const bf16x8*)&buf[(wm + fr) * 32 + kq];
        #pragma unroll
        for (int j = 0; j < 4; ++j) {
            bf16x8 bf = *(const bf16x8*)&buf[2048 + (j * 16 + fr) * 32 + kq];
            acc[j] = __builtin_amdgcn_mfma_f32_16x16x32_bf16(bf, af, acc[j], 0, 0, 0);
        }
        ++bufidx; if (bufidx == 3) bufidx = 0;
    }
    #undef STAGE_P

    const int quad = lane >> 4, col = lane & 15;
    const int m = bm + wm + col;
    #pragma unroll
    for (int j = 0; j < 4; ++j) {
        const int d0 = j * 16 + quad * 4;
        ushort4 o;
        o.x = f2bf(acc[j][0]); o.y = f2bf(acc[j][1]);
        o.z = f2bf(acc[j][2]); o.w = f2bf(acc[j][3]);
        *(ushort4*)(Ob + (size_t)m * 512 + hoff + d0) = o;
    }
}

// ---------- GLU: H bf16 [m,2048] -> G bf16 [m,1024] ----------
__global__ __launch_bounds__(256) void glu_kernel(
    const bf16u* __restrict__ H, bf16u* __restrict__ out, int total)
{
    const int idx = blockIdx.x * 256 + threadIdx.x;
    if (idx >= total) return;
    const int m = idx >> 10, c = idx & 1023;
    const float a = bf2f(H[(size_t)m * 2048 + c]);
    const float g = bf2f(H[(size_t)m * 2048 + 1024 + c]);
    out[idx] = f2bf(a * sigmoidf_(g));
}

// ---------- depthwise conv K=33, pad 16, register sliding window ----------
__global__ __launch_bounds__(256) void dwconv_kernel(
    const bf16u* __restrict__ in, const void* __restrict__ wp,
    bf16u* __restrict__ out, const int* __restrict__ flagp)
{
    const int f32 = *flagp;
    const int cb = blockIdx.x & 1;
    const int ttile = (blockIdx.x >> 1) & 127;
    const int b = blockIdx.x >> 8;
    const int t0 = ttile * 8;
    const int c = cb * 512 + threadIdx.x * 2;

    float w0[33], w1[33];
    if (f32) {
        const float* wf = (const float*)wp;
        #pragma unroll
        for (int k = 0; k < 33; ++k) { w0[k] = wf[c * 33 + k]; w1[k] = wf[(c + 1) * 33 + k]; }
    } else {
        const bf16u* wb = (const bf16u*)wp;
        #pragma unroll
        for (int k = 0; k < 33; ++k) { w0[k] = bf2f(wb[c * 33 + k]); w1[k] = bf2f(wb[(c + 1) * 33 + k]); }
    }

    unsigned win[40];
    #pragma unroll
    for (int r = 0; r < 40; ++r) {
        const int tt = t0 - 16 + r;
        win[r] = (tt >= 0 && tt < 1024)
               ? *(const unsigned*)(in + (size_t)(b * 1024 + tt) * 1024 + c)
               : 0u;
    }
    float acc0[8] = {}, acc1[8] = {};
    #pragma unroll
    for (int k = 0; k < 33; ++k) {
        #pragma unroll
        for (int dt = 0; dt < 8; ++dt) {
            const unsigned u = win[dt + k];
            acc0[dt] = fmaf(bf2f((bf16u)(u & 0xffffu)), w0[k], acc0[dt]);
            acc1[dt] = fmaf(bf2f((bf16u)(u >> 16)), w1[k], acc1[dt]);
        }
    }
    #pragma unroll
    for (int dt = 0; dt < 8; ++dt) {
        unsigned o = (unsigned)f2bf(acc0[dt]) | ((unsigned)f2bf(acc1[dt]) << 16);
        *(unsigned*)(out + (size_t)(b * 1024 + t0 + dt) * 1024 + c) = o;
    }
}

static inline void launch_gemm(const bf16u* A, const bf16u* Wt, const void* bias,
                               const float* res, void* C, int M, int N, int K,
                               float alpha, int act, int outbf, const int* flagp,
                               hipStream_t stream)
{
    if (N >= 1024) {
        dim3 grid(N / 128, M / 128);
        gemm_mfma<128><<<grid, 256, 0, stream>>>(A, Wt, bias, res, C, M, N, K, alpha, act, outbf, flagp);
    } else {
        dim3 grid(N / 128, M / 64);
        gemm_mfma<64><<<grid, 256, 0, stream>>>(A, Wt, bias, res, C, M, N, K, alpha, act, outbf, flagp);
    }
}

extern "C" void kernel_launch(void* const* d_in, const int* in_sizes, int n_in,
                              void* d_out, int out_size, void* d_ws, size_t ws_size,
                              hipStream_t stream)
{
    const void* x       = d_in[0];
    const void* pos_emb = d_in[1];
    const void* ln1_g   = d_in[2];
    const void* ln1_b   = d_in[3];
    const void* ffn1_w1 = d_in[4];
    const void* ffn1_b1 = d_in[5];
    const void* ffn1_w2 = d_in[6];
    const void* ffn1_b2 = d_in[7];
    const void* lnq_g   = d_in[8];
    const void* lnq_b   = d_in[9];
    const void* lnk_g   = d_in[10];
    const void* lnk_b   = d_in[11];
    const void* lnv_g   = d_in[12];
    const void* lnv_b   = d_in[13];
    const void* wq      = d_in[14];
    const void* wk      = d_in[15];
    const void* wv      = d_in[16];
    const void* wpos    = d_in[17];
    const void* pbu     = d_in[18];
    const void* pbv     = d_in[19];
    const void* wfc     = d_in[20];
    const void* cln_g   = d_in[21];
    const void* cln_b   = d_in[22];
    const void* pw1     = d_in[23];
    const void* dw_w    = d_in[24];
    const void* bn_g    = d_in[25];
    const void* bn_b    = d_in[26];
    const void* pw2     = d_in[27];
    const void* ln2_g   = d_in[28];
    const void* ln2_b   = d_in[29];
    const void* ffn2_w1 = d_in[30];
    const void* ffn2_b1 = d_in[31];
    const void* ffn2_w2 = d_in[32];
    const void* ffn2_b2 = d_in[33];
    const void* lnf_g   = d_in[34];
    const void* lnf_b   = d_in[35];

    const int BT = 8192;
    char* wsb = (char*)d_ws;
    float* act  = (float*)(wsb + 0);              // [8192,512] fp32 16MB, live all
    bf16u* qb   = (bf16u*)(wsb + 16777216);       // 8MB
    bf16u* kb   = (bf16u*)(wsb + 25165824);       // 8MB
    bf16u* vb   = (bf16u*)(wsb + 33554432);       // 8MB
    bf16u* pb   = (bf16u*)(wsb + 41943040);       // [1024,512] 1MB
    bf16u* tmpb = (bf16u*)(wsb + 42991616);       // [8192,512] 8MB LN out / obb
    bf16u* qu   = (bf16u*)(wsb + 51380224);       // 8MB
    bf16u* qv   = (bf16u*)(wsb + 59768832);       // 8MB
    bf16u* vt   = (bf16u*)(wsb + 68157440);       // [b][h][64][1024] 8MB
    bf16u* S    = (bf16u*)(wsb + 76546048);       // [2bb][8h][1024][1024] bf16 32MB
    bf16u* BD   = (bf16u*)(wsb + 110100480);      // 32MB
    bf16u* wc   = (bf16u*)(wsb + 143654912);      // weight cache 13.5MB
    int* flagp  = (int*)(wsb + 157810688);
    bf16u* obb  = tmpb;
    // phase-overlapped aliases (conv/FFN, after attention buffers die):
    bf16u* hbf  = (bf16u*)(wsb + 51380224);       // [8192,2048] bf16 32MB
    bf16u* Gbf  = (bf16u*)(wsb + 84934656);       // [8192,1024] 16MB
    bf16u* DWbf = (bf16u*)(wsb + 16777216);       // 16MB (over qb/kb)
    bf16u* LObf = (bf16u*)(wsb + 33554432);       // 16MB (over vb/pb/tmpb-start)

    bf16u* w_ffn1_1 = wc + 0;        // [2048,512]
    bf16u* w_ffn1_2 = wc + 1048576;  // [512,2048]
    bf16u* w_q      = wc + 2097152;
    bf16u* w_k      = wc + 2359296;
    bf16u* w_v      = wc + 2621440;
    bf16u* w_pos    = wc + 2883584;
    bf16u* w_fc     = wc + 3145728;
    bf16u* w_pw1    = wc + 3407872;  // [2048,512]
    bf16u* w_pw2    = wc + 4456448;  // [512,1024]
    bf16u* w_ffn2_1 = wc + 4980736;
    bf16u* w_ffn2_2 = wc + 6029312;

    // ---- dtype detection ----
    init_flag_kernel<<<1, 64, 0, stream>>>(flagp);
    detect_kernel<<<256, 256, 0, stream>>>(x, in_sizes[0], flagp);

    // ---- transposed bf16 weight cache (single dispatch) ----
    WTab tab;
    tab.w[0] = ffn1_w1; tab.wt[0] = w_ffn1_1; tab.K[0] = 512;  tab.N[0] = 2048;
    tab.w[1] = ffn1_w2; tab.wt[1] = w_ffn1_2; tab.K[1] = 2048; tab.N[1] = 512;
    tab.w[2] = wq;      tab.wt[2] = w_q;      tab.K[2] = 512;  tab.N[2] = 512;
    tab.w[3] = wk;      tab.wt[3] = w_k;      tab.K[3] = 512;  tab.N[3] = 512;
    tab.w[4] = wv;      tab.wt[4] = w_v;      tab.K[4] = 512;  tab.N[4] = 512;
    tab.w[5] = wpos;    tab.wt[5] = w_pos;    tab.K[5] = 512;  tab.N[5] = 512;
    tab.w[6] = wfc;     tab.wt[6] = w_fc;     tab.K[6] = 512;  tab.N[6] = 512;
    tab.w[7] = pw1;     tab.wt[7] = w_pw1;    tab.K[7] = 512;  tab.N[7] = 2048;
    tab.w[8] = pw2;     tab.wt[8] = w_pw2;    tab.K[8] = 1024; tab.N[8] = 512;
    tab.w[9] = ffn2_w1; tab.wt[9] = w_ffn2_1; tab.K[9] = 512;  tab.N[9] = 2048;
    tab.w[10] = ffn2_w2; tab.wt[10] = w_ffn2_2; tab.K[10] = 2048; tab.N[10] = 512;
    wtrans_all<<<dim3(64, 64, 11), 256, 0, stream>>>(tab, flagp);

    // ---- P = pos_emb @ wpos ----
    cvt_bf_kernel<<<2048, 256, 0, stream>>>(pos_emb, tmpb, 524288, flagp);
    launch_gemm(tmpb, w_pos, nullptr, nullptr, pb, 1024, 512, 512, 1.0f, 0, 1, flagp, stream);

    // ---- FFN1 half-step ----
    ln_kernel<512, 1, 0, false, true><<<BT, 256, 0, stream>>>(x, ln1_g, ln1_b, tmpb, act, flagp);
    launch_gemm(tmpb, w_ffn1_1, ffn1_b1, nullptr, hbf, BT, 2048, 512, 1.0f, 1, 1, flagp, stream);
    launch_gemm(hbf, w_ffn1_2, ffn1_b2, act, act, BT, 512, 2048, 0.5f, 0, 0, flagp, stream);

    // ---- MHSA projections ----
    ln_kernel<512, 0, 0, false, false><<<BT, 256, 0, stream>>>(act, lnq_g, lnq_b, tmpb, nullptr, flagp);
    launch_gemm(tmpb, w_q, nullptr, nullptr, qb, BT, 512, 512, 1.0f, 0, 1, flagp, stream);
    ln_kernel<512, 0, 0, false, false><<<BT, 256, 0, stream>>>(act, lnk_g, lnk_b, tmpb, nullptr, flagp);
    launch_gemm(tmpb, w_k, nullptr, nullptr, kb, BT, 512, 512, 1.0f, 0, 1, flagp, stream);
    ln_kernel<512, 0, 0, false, false><<<BT, 256, 0, stream>>>(act, lnv_g, lnv_b, tmpb, nullptr, flagp);
    launch_gemm(tmpb, w_v, nullptr, nullptr, vb, BT, 512, 512, 1.0f, 0, 1, flagp, stream);

    // ---- attention prep ----
    add_qbias_kernel<<<16384, 256, 0, stream>>>(qb, pbu, pbv, qu, qv, flagp);
    vtrans_kernel<<<dim3(32, 16, 8), 256, 0, stream>>>(vb, vt);

    // ---- attention, 2 batches per pass ----
    for (int b0 = 0; b0 < 8; b0 += 2) {
        const bf16u* qu_b = qu + (size_t)b0 * 524288;
        const bf16u* qv_b = qv + (size_t)b0 * 524288;
        const bf16u* kb_b = kb + (size_t)b0 * 524288;
        const bf16u* vt_b = vt + (size_t)b0 * 524288;
        bf16u* ob_b = obb + (size_t)b0 * 524288;
        attn_score_mfma<<<dim3(8, 8, 32), 256, 0, stream>>>(qu_b, qv_b, kb_b, pb, S, BD);
        attn_softmax_kernel<<<dim3(1024, 8, 2), 256, 0, stream>>>(S, BD);
        attn_pv_mfma<<<dim3(16, 8, 2), 256, 0, stream>>>(S, vt_b, ob_b);
    }
    launch_gemm(obb, w_fc, nullptr, act, act, BT, 512, 512, 1.0f, 0, 0, flagp, stream);

    // ---- convolution module ----
    ln_kernel<512, 0, 0, false, false><<<BT, 256, 0, stream>>>(act, cln_g, cln_b, tmpb, nullptr, flagp);
    launch_gemm(tmpb, w_pw1, nullptr, nullptr, hbf, BT, 2048, 512, 1.0f, 0, 1, flagp, stream);
    glu_kernel<<<32768, 256, 0, stream>>>(hbf, Gbf, 8388608);
    dwconv_kernel<<<2048, 256, 0, stream>>>(Gbf, dw_w, DWbf, flagp);
    ln_kernel<1024, 2, 0, true, false><<<BT, 256, 0, stream>>>(DWbf, bn_g, bn_b, LObf, nullptr, flagp);
    launch_gemm(LObf, w_pw2, nullptr, act, act, BT, 512, 1024, 1.0f, 0, 0, flagp, stream);

    // ---- FFN2 half-step ----
    ln_kernel<512, 0, 0, false, false><<<BT, 256, 0, stream>>>(act, ln2_g, ln2_b, tmpb, nullptr, flagp);
    launch_gemm(tmpb, w_ffn2_1, ffn2_b1, nullptr, hbf, BT, 2048, 512, 1.0f, 1, 1, flagp, stream);
    launch_gemm(hbf, w_ffn2_2, ffn2_b2, act, act, BT, 512, 2048, 0.5f, 0, 0, flagp, stream);

    // ---- final LN -> d_out ----
    ln_kernel<512, 0, 1, false, false><<<BT, 256, 0, stream>>>(act, lnf_g, lnf_b, d_out, nullptr, flagp);
}

// Round 11
// 779.218 us; speedup vs baseline: 1.2769x; 1.2769x over previous
//
#include <hip/hip_runtime.h>

// ---------- types / helpers ----------
typedef unsigned short bf16u;
typedef __attribute__((ext_vector_type(8))) short bf16x8;   // MFMA A/B frag (4 VGPR)
typedef __attribute__((ext_vector_type(4))) float f32x4;    // MFMA C/D frag

__device__ __forceinline__ float bf2f(bf16u u) {
    return __uint_as_float(((unsigned)u) << 16);
}
__device__ __forceinline__ bf16u f2bf(float f) {
    unsigned u = __float_as_uint(f);
    unsigned r = (u + 0x7fffu + ((u >> 16) & 1u)) >> 16;
    return (bf16u)r;
}
__device__ __forceinline__ float sigmoidf_(float x) {
    return 1.0f / (1.0f + __expf(-x));
}

// direct global->LDS 16B copy: lane i of the wave lands at ldst + i*16B.
__device__ __forceinline__ void gload_lds16(const bf16u* g, bf16u* l) {
    __builtin_amdgcn_global_load_lds(
        (const __attribute__((address_space(1))) unsigned int*)(const void*)g,
        (__attribute__((address_space(3))) unsigned int*)(void*)l, 16, 0, 0);
}

// ---------- dtype detection (flag=1 -> raw inputs fp32, 0 -> bf16) ----------
__global__ void init_flag_kernel(int* flag) {
    if (threadIdx.x == 0 && blockIdx.x == 0) *flag = 0;
}
__global__ __launch_bounds__(256) void detect_kernel(
    const void* x, int nelem, int* flag)
{
    const int scan = nelem < (1 << 20) ? nelem : (1 << 20);
    const bf16u* p = (const bf16u*)x;
    int bad = 0;
    for (int j = blockIdx.x * 256 + threadIdx.x; j < scan; j += 65536) {
        unsigned u = p[j];
        if ((u & 0x7F80u) == 0x7F80u) bad = 1;
    }
    if (bad) atomicOr(flag, 1);
}

// ---------- convert raw (bf16/fp32 per flag) -> bf16 ----------
__global__ __launch_bounds__(256) void cvt_bf_kernel(
    const void* __restrict__ in, bf16u* __restrict__ out, int n,
    const int* __restrict__ flagp)
{
    const int f32 = *flagp;
    const int i = blockIdx.x * 256 + threadIdx.x;
    if (i >= n) return;
    if (f32) out[i] = f2bf(((const float*)in)[i]);
    else     out[i] = ((const bf16u*)in)[i];
}

// ---------- folded-bias init: bias_qkv=0, bias_ffn1=b1, bias_pw1=0, bias_ffn2=b1 ----------
__global__ __launch_bounds__(256) void bias_init_kernel(
    float* bias_qkv, float* bias_ffn1, const void* ffn1_b1,
    float* bias_pw1, float* bias_ffn2, const void* ffn2_b1,
    const int* __restrict__ flagp)
{
    const int f32 = *flagp;
    const int i = blockIdx.x * 256 + threadIdx.x;
    if (i < 1536) bias_qkv[i] = 0.f;
    if (i < 2048) {
        bias_ffn1[i] = f32 ? ((const float*)ffn1_b1)[i] : bf2f(((const bf16u*)ffn1_b1)[i]);
        bias_pw1[i]  = 0.f;
        bias_ffn2[i] = f32 ? ((const float*)ffn2_b1)[i] : bf2f(((const bf16u*)ffn2_b1)[i]);
    }
}

// ---------- weight transpose + LN gain/bias fold, all in one dispatch ----------
// Wt[n,k] = g[k]*W[k,n]; bias_dest[n] += sum_k b[k]*W[k,n] (atomicAdd).
struct WTab {
    const void* w[11];
    bf16u* wt[11];
    const void* g[11];   // gain to fold (raw) or null
    const void* bs[11];  // LN bias source (raw) or null
    float* bd[11];       // folded-bias dest (fp32) or null
    int K[11];
    int N[11];
};
__global__ __launch_bounds__(256) void wtrans_all(
    WTab tab, const int* __restrict__ flagp)
{
    __shared__ float tile[32][33];
    __shared__ float bpart[8][33];
    const int id = blockIdx.z;
    const int K = tab.K[id], N = tab.N[id];
    const int n0 = blockIdx.x * 32, k0 = blockIdx.y * 32;
    if (n0 >= N || k0 >= K) return;
    const void* W = tab.w[id];
    bf16u* Wt = tab.wt[id];
    const void* gv = tab.g[id];
    const void* bsv = tab.bs[id];
    float* bdv = tab.bd[id];
    const int f32 = *flagp;
    const int tx = threadIdx.x & 31, ty = threadIdx.x >> 5;
    float bacc = 0.f;
    #pragma unroll
    for (int r = 0; r < 4; ++r) {
        const int k = ty + r * 8;
        float v;
        if (f32) v = ((const float*)W)[(size_t)(k0 + k) * N + n0 + tx];
        else     v = bf2f(((const bf16u*)W)[(size_t)(k0 + k) * N + n0 + tx]);
        if (bsv) {
            float b = f32 ? ((const float*)bsv)[k0 + k]
                          : bf2f(((const bf16u*)bsv)[k0 + k]);
            bacc += b * v;
        }
        if (gv) {
            float g = f32 ? ((const float*)gv)[k0 + k]
                          : bf2f(((const bf16u*)gv)[k0 + k]);
            v *= g;
        }
        tile[k][tx] = v;
    }
    if (bsv) bpart[ty][tx] = bacc;
    __syncthreads();
    #pragma unroll
    for (int r = 0; r < 4; ++r) {
        const int n = ty + r * 8;
        Wt[(size_t)(n0 + n) * K + k0 + tx] = f2bf(tile[tx][n]);
    }
    if (bsv && ty == 0) {
        float t = 0.f;
        #pragma unroll
        for (int r = 0; r < 8; ++r) t += bpart[r][tx];
        atomicAdd(bdv + n0 + tx, t);
    }
}

// ---------- V transpose: qkv v-slice [row][1536] -> vt [b][h][64 d][1024 j] ----------
__global__ __launch_bounds__(256) void vtrans_kernel(
    const bf16u* __restrict__ vsl, bf16u* __restrict__ vt)
{
    __shared__ bf16u tile[32][33];
    const int j0 = blockIdx.x * 32;
    const int h = blockIdx.y >> 1, dt = (blockIdx.y & 1) * 32;
    const int b = blockIdx.z;
    const int tx = threadIdx.x & 31, ty = threadIdx.x >> 5;
    #pragma unroll
    for (int r = 0; r < 4; ++r) {
        const int j = ty + r * 8;
        tile[j][tx] = vsl[(size_t)(b * 1024 + j0 + j) * 1536 + h * 64 + dt + tx];
    }
    __syncthreads();
    #pragma unroll
    for (int r = 0; r < 4; ++r) {
        const int d = ty + r * 8;
        vt[(size_t)((b * 8 + h) * 64 + dt + d) * 1024 + j0 + tx] = tile[tx][d];
    }
}

// ---------- qu/qv = q + bias_u/v (q from qkv buffer, stride 1536) ----------
__global__ __launch_bounds__(256) void add_qbias_kernel(
    const bf16u* __restrict__ qkvb, const void* __restrict__ bu,
    const void* __restrict__ bv, bf16u* __restrict__ qu,
    bf16u* __restrict__ qv, const int* __restrict__ flagp)
{
    const int f32 = *flagp;
    const int idx = blockIdx.x * 256 + threadIdx.x;
    const int row = idx >> 9, c = idx & 511;
    const float q = bf2f(qkvb[(size_t)row * 1536 + c]);
    float ub, vbias;
    if (f32) { ub = ((const float*)bu)[c]; vbias = ((const float*)bv)[c]; }
    else     { ub = bf2f(((const bf16u*)bu)[c]); vbias = bf2f(((const bf16u*)bv)[c]); }
    qu[idx] = f2bf(q + ub);
    qv[idx] = f2bf(q + vbias);
}

// ---------- LayerNorm ----------
// IN_MODE: 0=fp32 ws, 1=raw (flag dtype), 2=bf16 ws.
// OUT_MODE: 0=bf16 ws, 1=raw d_out (flag dtype). GB: apply gain/bias.
template <int D, int IN_MODE, int OUT_MODE, bool SILU, bool COPY, bool GB>
__global__ __launch_bounds__(256) void ln_kernel(
    const void* __restrict__ in_, const void* __restrict__ gvec,
    const void* __restrict__ bvec, void* __restrict__ out_,
    float* __restrict__ copy_out, const int* __restrict__ flagp)
{
    constexpr int VPT = D / 256;
    const int f32 = *flagp;
    const int row = blockIdx.x;
    const int tid = threadIdx.x;
    const size_t base = (size_t)row * D;
    float x[VPT];
    if (IN_MODE == 2 || (IN_MODE == 1 && !f32)) {
        const bf16u* in = (const bf16u*)in_;
        #pragma unroll
        for (int i = 0; i < VPT; ++i) x[i] = bf2f(in[base + tid + i * 256]);
    } else {
        const float* in = (const float*)in_;
        #pragma unroll
        for (int i = 0; i < VPT; ++i) x[i] = in[base + tid + i * 256];
    }
    float s = 0.f, q = 0.f;
    #pragma unroll
    for (int i = 0; i < VPT; ++i) { s += x[i]; q += x[i] * x[i]; }
    __shared__ float red[10];
    #pragma unroll
    for (int off = 32; off; off >>= 1) {
        s += __shfl_down(s, off, 64);
        q += __shfl_down(q, off, 64);
    }
    const int lane = tid & 63, wv = tid >> 6;
    if (lane == 0) { red[wv] = s; red[4 + wv] = q; }
    __syncthreads();
    if (tid == 0) {
        float ts = red[0] + red[1] + red[2] + red[3];
        float tq = red[4] + red[5] + red[6] + red[7];
        float mean = ts / (float)D;
        float var = tq / (float)D - mean * mean;
        red[8] = mean;
        red[9] = rsqrtf(var + 1e-5f);
    }
    __syncthreads();
    const float mean = red[8], rstd = red[9];
    #pragma unroll
    for (int i = 0; i < VPT; ++i) {
        const int c = tid + i * 256;
        float v = (x[i] - mean) * rstd;
        if (GB) {
            float gv, bv;
            if (f32) {
                gv = ((const float*)gvec)[c];
                bv = ((const float*)bvec)[c];
            } else {
                gv = bf2f(((const bf16u*)gvec)[c]);
                bv = bf2f(((const bf16u*)bvec)[c]);
            }
            v = v * gv + bv;
        }
        if (SILU) v *= sigmoidf_(v);
        if (OUT_MODE == 0) {
            ((bf16u*)out_)[base + c] = f2bf(v);
        } else {
            if (f32) ((float*)out_)[base + c] = v;
            else     ((bf16u*)out_)[base + c] = f2bf(v);
        }
        if (COPY) copy_out[base + c] = x[i];
    }
}

// ---------- MFMA GEMM: C = res + alpha * act(A @ Wt^T + bias) ----------
// Round-9 structure: all-LDS staging, 3-stage pipeline, manual vmcnt+s_barrier,
// XCD swizzle (m-fast), swapped-operand D layout -> vector epilogue.
// biasf: fp32 folded bias (or null); biasr: raw bias per flag (or null).
template <int TM>
__global__ __launch_bounds__(256) void gemm_mfma(
    const bf16u* __restrict__ A, const bf16u* __restrict__ Wt,
    const float* __restrict__ biasf, const void* __restrict__ biasr,
    const float* __restrict__ res, void* __restrict__ C,
    int M, int N, int K, float alpha, int act, int outbf,
    const int* __restrict__ flagp)
{
    constexpr int CHUNKS_A = TM * 4;
    constexpr int TOT = CHUNKS_A + 512;
    constexpr int CPW = TOT / 4;
    constexpr int ISSUES = CPW / 64;
    constexpr int BUFSZ = (TM + 128) * 32;
    constexpr int MI = 4;
    constexpr int NJ = (TM == 128) ? 4 : 2;
    __shared__ bf16u sh[3 * BUFSZ];
    const int f32 = *flagp;
    const int tid = threadIdx.x;
    const int mtiles = M / TM;
    const int lid = blockIdx.y * gridDim.x + blockIdx.x;
    const int bm = (lid % mtiles) * TM;
    const int bn = (lid / mtiles) * 128;
    const int lane = tid & 63, wvid = tid >> 6;
    const int wm = (TM == 128) ? (wvid >> 1) * 64 : 0;
    const int wn = (TM == 128) ? (wvid & 1) * 64 : wvid * 32;

    f32x4 acc[MI][NJ];
    {
        f32x4 z = {0.f, 0.f, 0.f, 0.f};
        #pragma unroll
        for (int i = 0; i < MI; ++i)
            #pragma unroll
            for (int j = 0; j < NJ; ++j) acc[i][j] = z;
    }
    const int kq = (lane >> 4) * 8, fr = lane & 15;

    #define STAGE_G(k0, bufp)                                                   \
    {                                                                           \
        bf16u* base_ = (bufp);                                                  \
        _Pragma("unroll")                                                       \
        for (int t = 0; t < ISSUES; ++t) {                                      \
            const int cc = wvid * CPW + t * 64 + lane;                          \
            const bf16u* src_;                                                  \
            if (cc < CHUNKS_A)                                                  \
                src_ = A + (size_t)(bm + (cc >> 2)) * K + (k0) + (cc & 3) * 8;  \
            else {                                                              \
                const int cb_ = cc - CHUNKS_A;                                  \
                src_ = Wt + (size_t)(bn + (cb_ >> 2)) * K + (k0) + (cb_ & 3) * 8;\
            }                                                                   \
            gload_lds16(src_, base_ + (wvid * CPW + t * 64) * 8);               \
        }                                                                       \
    }

    const int KT = K / 32;
    STAGE_G(0, sh);
    STAGE_G(32, sh + BUFSZ);
    int bufidx = 0;
    for (int kt = 0; kt < KT; ++kt) {
        if (kt + 1 < KT)
            asm volatile("s_waitcnt vmcnt(%0)\ns_barrier" :: "i"(ISSUES) : "memory");
        else
            asm volatile("s_waitcnt vmcnt(0)\ns_barrier" ::: "memory");
        if (kt + 2 < KT) {
            int nb = bufidx + 2; if (nb >= 3) nb -= 3;
            STAGE_G((kt + 2) * 32, sh + nb * BUFSZ);
        }
        const bf16u* buf = sh + bufidx * BUFSZ;
        bf16x8 af[MI], bfr[NJ];
        #pragma unroll
        for (int i = 0; i < MI; ++i)
            af[i] = *(const bf16x8*)&buf[(wm + i * 16 + fr) * 32 + kq];
        #pragma unroll
        for (int j = 0; j < NJ; ++j)
            bfr[j] = *(const bf16x8*)&buf[TM * 32 + (wn + j * 16 + fr) * 32 + kq];
        #pragma unroll
        for (int i = 0; i < MI; ++i)
            #pragma unroll
            for (int j = 0; j < NJ; ++j)
                acc[i][j] = __builtin_amdgcn_mfma_f32_16x16x32_bf16(
                    bfr[j], af[i], acc[i][j], 0, 0, 0);
        ++bufidx; if (bufidx == 3) bufidx = 0;
    }
    #undef STAGE_G

    // epilogue: D[n = quad*4+reg][m = lane&15] -> vector stores
    const int quad = lane >> 4, col = lane & 15;
    #pragma unroll
    for (int j = 0; j < NJ; ++j) {
        const int n0 = bn + wn + j * 16 + quad * 4;
        float4 bv4 = {0.f, 0.f, 0.f, 0.f};
        if (biasf) {
            bv4 = *(const float4*)(biasf + n0);
        } else if (biasr) {
            if (f32) bv4 = *(const float4*)((const float*)biasr + n0);
            else {
                ushort4 bu = *(const ushort4*)((const bf16u*)biasr + n0);
                bv4.x = bf2f(bu.x); bv4.y = bf2f(bu.y);
                bv4.z = bf2f(bu.z); bv4.w = bf2f(bu.w);
            }
        }
        #pragma unroll
        for (int i = 0; i < MI; ++i) {
            const int m = bm + wm + i * 16 + col;
            const size_t off = (size_t)m * N + n0;
            float v[4];
            #pragma unroll
            for (int r = 0; r < 4; ++r) {
                float t = acc[i][j][r] + ((const float*)&bv4)[r];
                if (act == 1) t *= sigmoidf_(t);
                v[r] = t * alpha;
            }
            if (res) {
                float4 r4 = *(const float4*)(res + off);
                v[0] += r4.x; v[1] += r4.y; v[2] += r4.z; v[3] += r4.w;
            }
            if (outbf) {
                ushort4 o;
                o.x = f2bf(v[0]); o.y = f2bf(v[1]);
                o.z = f2bf(v[2]); o.w = f2bf(v[3]);
                *(ushort4*)((bf16u*)C + off) = o;
            } else {
                float4 o = {v[0], v[1], v[2], v[3]};
                *(float4*)((float*)C + off) = o;
            }
        }
    }
}

// ---------- attention score MFMA (dbuf, 2 batches, swapped epilogue) ----------
// grid (8 jt, 8 it, 32): z: h=z&7, bb=(z>>3)&1, which=z>>4.
// which=0: S = (qu @ k^T)*scale (k slice stride 1536); which=1: BD = (qv @ pb^T)*scale.
__global__ __launch_bounds__(256) void attn_score_mfma(
    const bf16u* __restrict__ qu, const bf16u* __restrict__ qv,
    const bf16u* __restrict__ ksl, const bf16u* __restrict__ pb,
    bf16u* __restrict__ S, bf16u* __restrict__ BD)
{
    constexpr int BUFSZ = 8192;
    __shared__ bf16u sh[2 * BUFSZ];
    const int tid = threadIdx.x;
    const int z = blockIdx.z;
    const int h = z & 7, bb = (z >> 3) & 1, which = z >> 4;
    const bf16u* A = (which ? qv : qu) + (size_t)bb * 524288;
    const bf16u* B;
    int sB;
    if (which) { B = pb; sB = 512; }
    else       { B = ksl + (size_t)bb * 1572864; sB = 1536; }
    bf16u* C = (which ? BD : S) + (size_t)(bb * 8 + h) * 1048576;
    const int hoff = h * 64;
    const int bm = blockIdx.y * 128, bn = blockIdx.x * 128;
    const int lane = tid & 63, wvid = tid >> 6;
    const int wm = (wvid >> 1) * 64, wn = (wvid & 1) * 64;
    const int kq = (lane >> 4) * 8, fr = lane & 15;

    f32x4 acc[4][4];
    {
        f32x4 zr = {0.f, 0.f, 0.f, 0.f};
        #pragma unroll
        for (int i = 0; i < 4; ++i)
            #pragma unroll
            for (int j = 0; j < 4; ++j) acc[i][j] = zr;
    }

    #define STAGE_S(k0, bsel)                                                   \
    {                                                                           \
        bf16u* base_ = sh + (bsel) * BUFSZ;                                     \
        _Pragma("unroll")                                                       \
        for (int t = 0; t < 4; ++t) {                                           \
            const int cc = wvid * 256 + t * 64 + lane;                          \
            const bf16u* src_;                                                  \
            if (cc < 512)                                                       \
                src_ = A + (size_t)(bm + (cc >> 2)) * 512 + hoff + (k0) + (cc & 3) * 8; \
            else {                                                              \
                const int cb_ = cc - 512;                                       \
                src_ = B + (size_t)(bn + (cb_ >> 2)) * sB + hoff + (k0) + (cb_ & 3) * 8; \
            }                                                                   \
            gload_lds16(src_, base_ + (wvid * 256 + t * 64) * 8);               \
        }                                                                       \
    }

    STAGE_S(0, 0);
    #pragma unroll
    for (int kt = 0; kt < 2; ++kt) {
        __syncthreads();
        if (kt == 0) STAGE_S(32, 1);
        const bf16u* buf = sh + (kt & 1) * BUFSZ;
        bf16x8 af[4], bfr[4];
        #pragma unroll
        for (int i = 0; i < 4; ++i)
            af[i] = *(const bf16x8*)&buf[(wm + i * 16 + fr) * 32 + kq];
        #pragma unroll
        for (int j = 0; j < 4; ++j)
            bfr[j] = *(const bf16x8*)&buf[4096 + (wn + j * 16 + fr) * 32 + kq];
        #pragma unroll
        for (int i = 0; i < 4; ++i)
            #pragma unroll
            for (int j = 0; j < 4; ++j)
                acc[i][j] = __builtin_amdgcn_mfma_f32_16x16x32_bf16(
                    bfr[j], af[i], acc[i][j], 0, 0, 0);
    }
    #undef STAGE_S

    const int quad = lane >> 4, col = lane & 15;
    #pragma unroll
    for (int j = 0; j < 4; ++j) {
        const int n0 = bn + wn + j * 16 + quad * 4;
        #pragma unroll
        for (int i = 0; i < 4; ++i) {
            const int m = bm + wm + i * 16 + col;
            ushort4 o;
            o.x = f2bf(acc[i][j][0] * 0.125f);
            o.y = f2bf(acc[i][j][1] * 0.125f);
            o.z = f2bf(acc[i][j][2] * 0.125f);
            o.w = f2bf(acc[i][j][3] * 0.125f);
            *(ushort4*)(C + (size_t)m * 1024 + n0) = o;
        }
    }
}

// ---------- softmax with rel-shift gather (bf16 S/BD, probs in-place, 2 batches) ----------
__global__ __launch_bounds__(256) void attn_softmax_kernel(
    bf16u* __restrict__ S, const bf16u* __restrict__ BD)
{
    const int i = blockIdx.x, h = blockIdx.y, bb = blockIdx.z;
    const int tid = threadIdx.x;
    const size_t hb = (size_t)(bb * 8 + h) * 1048576;
    bf16u* srow = S + hb + (size_t)i * 1024;
    const bf16u* bd0 = BD + hb + (size_t)i * 1024;
    const bf16u* bd1 = bd0 + 1024;
    float v[4];
    #pragma unroll
    for (int k = 0; k < 4; ++k) {
        const int j = tid + k * 256;
        float bd;
        if (j <= i)          bd = bf2f(bd0[1023 - i + j]);
        else if (j == i + 1) bd = 0.f;
        else                 bd = bf2f(bd1[j - i - 2]);
        v[k] = bf2f(srow[j]) + bd;
    }
    __shared__ float red[6];
    float m = fmaxf(fmaxf(v[0], v[1]), fmaxf(v[2], v[3]));
    #pragma unroll
    for (int off = 32; off; off >>= 1) m = fmaxf(m, __shfl_down(m, off, 64));
    const int lane = tid & 63, w = tid >> 6;
    if (lane == 0) red[w] = m;
    __syncthreads();
    if (tid == 0) red[4] = fmaxf(fmaxf(red[0], red[1]), fmaxf(red[2], red[3]));
    __syncthreads();
    m = red[4];
    float e[4], l = 0.f;
    #pragma unroll
    for (int k = 0; k < 4; ++k) { e[k] = __expf(v[k] - m); l += e[k]; }
    #pragma unroll
    for (int off = 32; off; off >>= 1) l += __shfl_down(l, off, 64);
    if (lane == 0) red[w] = l;
    __syncthreads();
    if (tid == 0) red[5] = red[0] + red[1] + red[2] + red[3];
    __syncthreads();
    const float inv = 1.0f / red[5];
    #pragma unroll
    for (int k = 0; k < 4; ++k) srow[tid + k * 256] = f2bf(e[k] * inv);
}

// ---------- attention PV MFMA (3-stage pipeline, 2 batches, swapped epilogue) ----------
// grid (16 i-tiles, 8 h, 2 bb). Tile M=64 i x N=64 d, K=1024 j.
__global__ __launch_bounds__(256) void attn_pv_mfma(
    const bf16u* __restrict__ P, const bf16u* __restrict__ Vt,
    bf16u* __restrict__ O)
{
    constexpr int BUFSZ = 4096;
    __shared__ bf16u sh[3 * BUFSZ];
    const int tid = threadIdx.x;
    const int h = blockIdx.y, bb = blockIdx.z;
    const int bm = blockIdx.x * 64;
    const int hoff = h * 64;
    const bf16u* Ph = P + (size_t)(bb * 8 + h) * 1048576;
    const bf16u* Vh = Vt + (size_t)bb * 524288 + (size_t)h * 65536;
    bf16u* Ob = O + (size_t)bb * 524288;
    const int lane = tid & 63, wvid = tid >> 6;
    const int wm = wvid * 16;
    const int kq = (lane >> 4) * 8, fr = lane & 15;

    f32x4 acc[4];
    {
        f32x4 z = {0.f, 0.f, 0.f, 0.f};
        #pragma unroll
        for (int j = 0; j < 4; ++j) acc[j] = z;
    }

    #define STAGE_P(k0, bufp)                                                   \
    {                                                                           \
        bf16u* base_ = (bufp);                                                  \
        _Pragma("unroll")                                                       \
        for (int t = 0; t < 2; ++t) {                                           \
            const int cc = wvid * 128 + t * 64 + lane;                          \
            const bf16u* src_;                                                  \
            if (cc < 256)                                                       \
                src_ = Ph + (size_t)(bm + (cc >> 2)) * 1024 + (k0) + (cc & 3) * 8; \
            else {                                                              \
                const int cb_ = cc - 256;                                       \
                src_ = Vh + (size_t)(cb_ >> 2) * 1024 + (k0) + (cb_ & 3) * 8;   \
            }                                                                   \
            gload_lds16(src_, base_ + (wvid * 128 + t * 64) * 8);               \
        }                                                                       \
    }

    STAGE_P(0, sh);
    STAGE_P(32, sh + BUFSZ);
    int bufidx = 0;
    for (int kt = 0; kt < 32; ++kt) {
        if (kt + 1 < 32)
            asm volatile("s_waitcnt vmcnt(2)\ns_barrier" ::: "memory");
        else
            asm volatile("s_waitcnt vmcnt(0)\ns_barrier" ::: "memory");
        if (kt + 2 < 32) {
            int nb = bufidx + 2; if (nb >= 3) nb -= 3;
            STAGE_P((kt + 2) * 32, sh + nb * BUFSZ);
        }
        const bf16u* buf = sh + bufidx * BUFSZ;
        bf16x8 af = *(const bf16x8*)&buf[(wm + fr) * 32 + kq];
        #pragma unroll
        for (int j = 0; j < 4; ++j) {
            bf16x8 bf = *(const bf16x8*)&buf[2048 + (j * 16 + fr) * 32 + kq];
            acc[j] = __builtin_amdgcn_mfma_f32_16x16x32_bf16(bf, af, acc[j], 0, 0, 0);
        }
        ++bufidx; if (bufidx == 3) bufidx = 0;
    }
    #undef STAGE_P

    const int quad = lane >> 4, col = lane & 15;
    const int m = bm + wm + col;
    #pragma unroll
    for (int j = 0; j < 4; ++j) {
        const int d0 = j * 16 + quad * 4;
        ushort4 o;
        o.x = f2bf(acc[j][0]); o.y = f2bf(acc[j][1]);
        o.z = f2bf(acc[j][2]); o.w = f2bf(acc[j][3]);
        *(ushort4*)(Ob + (size_t)m * 512 + hoff + d0) = o;
    }
}

// ---------- GLU: H bf16 [m,2048] -> G bf16 [m,1024] ----------
__global__ __launch_bounds__(256) void glu_kernel(
    const bf16u* __restrict__ H, bf16u* __restrict__ out, int total)
{
    const int idx = blockIdx.x * 256 + threadIdx.x;
    if (idx >= total) return;
    const int m = idx >> 10, c = idx & 1023;
    const float a = bf2f(H[(size_t)m * 2048 + c]);
    const float g = bf2f(H[(size_t)m * 2048 + 1024 + c]);
    out[idx] = f2bf(a * sigmoidf_(g));
}

// ---------- depthwise conv K=33, pad 16, register sliding window ----------
__global__ __launch_bounds__(256) void dwconv_kernel(
    const bf16u* __restrict__ in, const void* __restrict__ wp,
    bf16u* __restrict__ out, const int* __restrict__ flagp)
{
    const int f32 = *flagp;
    const int cb = blockIdx.x & 1;
    const int ttile = (blockIdx.x >> 1) & 127;
    const int b = blockIdx.x >> 8;
    const int t0 = ttile * 8;
    const int c = cb * 512 + threadIdx.x * 2;

    float w0[33], w1[33];
    if (f32) {
        const float* wf = (const float*)wp;
        #pragma unroll
        for (int k = 0; k < 33; ++k) { w0[k] = wf[c * 33 + k]; w1[k] = wf[(c + 1) * 33 + k]; }
    } else {
        const bf16u* wb = (const bf16u*)wp;
        #pragma unroll
        for (int k = 0; k < 33; ++k) { w0[k] = bf2f(wb[c * 33 + k]); w1[k] = bf2f(wb[(c + 1) * 33 + k]); }
    }

    unsigned win[40];
    #pragma unroll
    for (int r = 0; r < 40; ++r) {
        const int tt = t0 - 16 + r;
        win[r] = (tt >= 0 && tt < 1024)
               ? *(const unsigned*)(in + (size_t)(b * 1024 + tt) * 1024 + c)
               : 0u;
    }
    float acc0[8] = {}, acc1[8] = {};
    #pragma unroll
    for (int k = 0; k < 33; ++k) {
        #pragma unroll
        for (int dt = 0; dt < 8; ++dt) {
            const unsigned u = win[dt + k];
            acc0[dt] = fmaf(bf2f((bf16u)(u & 0xffffu)), w0[k], acc0[dt]);
            acc1[dt] = fmaf(bf2f((bf16u)(u >> 16)), w1[k], acc1[dt]);
        }
    }
    #pragma unroll
    for (int dt = 0; dt < 8; ++dt) {
        unsigned o = (unsigned)f2bf(acc0[dt]) | ((unsigned)f2bf(acc1[dt]) << 16);
        *(unsigned*)(out + (size_t)(b * 1024 + t0 + dt) * 1024 + c) = o;
    }
}

static inline void launch_gemm(const bf16u* A, const bf16u* Wt,
                               const float* biasf, const void* biasr,
                               const float* res, void* C, int M, int N, int K,
                               float alpha, int act, int outbf, const int* flagp,
                               hipStream_t stream)
{
    if (N >= 1024) {
        dim3 grid(N / 128, M / 128);
        gemm_mfma<128><<<grid, 256, 0, stream>>>(A, Wt, biasf, biasr, res, C, M, N, K, alpha, act, outbf, flagp);
    } else {
        dim3 grid(N / 128, M / 64);
        gemm_mfma<64><<<grid, 256, 0, stream>>>(A, Wt, biasf, biasr, res, C, M, N, K, alpha, act, outbf, flagp);
    }
}

extern "C" void kernel_launch(void* const* d_in, const int* in_sizes, int n_in,
                              void* d_out, int out_size, void* d_ws, size_t ws_size,
                              hipStream_t stream)
{
    const void* x       = d_in[0];
    const void* pos_emb = d_in[1];
    const void* ln1_g   = d_in[2];
    const void* ln1_b   = d_in[3];
    const void* ffn1_w1 = d_in[4];
    const void* ffn1_b1 = d_in[5];
    const void* ffn1_w2 = d_in[6];
    const void* ffn1_b2 = d_in[7];
    const void* lnq_g   = d_in[8];
    const void* lnq_b   = d_in[9];
    const void* lnk_g   = d_in[10];
    const void* lnk_b   = d_in[11];
    const void* lnv_g   = d_in[12];
    const void* lnv_b   = d_in[13];
    const void* wq      = d_in[14];
    const void* wk      = d_in[15];
    const void* wv      = d_in[16];
    const void* wpos    = d_in[17];
    const void* pbu     = d_in[18];
    const void* pbv     = d_in[19];
    const void* wfc     = d_in[20];
    const void* cln_g   = d_in[21];
    const void* cln_b   = d_in[22];
    const void* pw1     = d_in[23];
    const void* dw_w    = d_in[24];
    const void* bn_g    = d_in[25];
    const void* bn_b    = d_in[26];
    const void* pw2     = d_in[27];
    const void* ln2_g   = d_in[28];
    const void* ln2_b   = d_in[29];
    const void* ffn2_w1 = d_in[30];
    const void* ffn2_b1 = d_in[31];
    const void* ffn2_w2 = d_in[32];
    const void* ffn2_b2 = d_in[33];
    const void* lnf_g   = d_in[34];
    const void* lnf_b   = d_in[35];

    const int BT = 8192;
    char* wsb = (char*)d_ws;
    float* act   = (float*)(wsb + 0);             // [8192,512] fp32 16MB, live all
    bf16u* qkvb  = (bf16u*)(wsb + 16777216);      // [8192,1536] 24MB (q|k|v slices)
    bf16u* pb    = (bf16u*)(wsb + 41943040);      // [1024,512] 1MB
    bf16u* tmpb  = (bf16u*)(wsb + 42991616);      // [8192,512] 8MB LN out / obb
    bf16u* qu    = (bf16u*)(wsb + 51380224);      // 8MB
    bf16u* qv    = (bf16u*)(wsb + 59768832);      // 8MB
    bf16u* vt    = (bf16u*)(wsb + 68157440);      // [b][h][64][1024] 8MB
    bf16u* S     = (bf16u*)(wsb + 76546048);      // [2bb][8h][1024][1024] 32MB
    bf16u* BD    = (bf16u*)(wsb + 110100480);     // 32MB
    bf16u* wc    = (bf16u*)(wsb + 143654912);     // weight cache 13.5MB
    int* flagp   = (int*)(wsb + 157810688);
    float* biasb = (float*)(wsb + 157811712);     // folded biases (7680 f)
    bf16u* obb   = tmpb;
    // phase-overlapped aliases (conv/FFN, after attention buffers die):
    bf16u* hbf   = (bf16u*)(wsb + 51380224);      // [8192,2048] 32MB
    bf16u* Gbf   = (bf16u*)(wsb + 84934656);      // [8192,1024] 16MB
    bf16u* DWbf  = (bf16u*)(wsb + 16777216);      // 16MB (over qkvb)
    bf16u* LObf  = (bf16u*)(wsb + 33554432);      // 16MB (over qkvb tail/pb)

    bf16u* w_ffn1_1 = wc + 0;        // [2048,512]
    bf16u* w_ffn1_2 = wc + 1048576;  // [512,2048]
    bf16u* w_qkv    = wc + 2097152;  // [1536,512]
    bf16u* w_pos    = wc + 2883584;  // [512,512]
    bf16u* w_fc     = wc + 3145728;
    bf16u* w_pw1    = wc + 3407872;  // [2048,512]
    bf16u* w_pw2    = wc + 4456448;  // [512,1024]
    bf16u* w_ffn2_1 = wc + 4980736;
    bf16u* w_ffn2_2 = wc + 6029312;

    float* bias_qkv  = biasb + 0;     // 1536
    float* bias_ffn1 = biasb + 1536;  // 2048
    float* bias_pw1  = biasb + 3584;  // 2048
    float* bias_ffn2 = biasb + 5632;  // 2048

    // ---- dtype detection ----
    init_flag_kernel<<<1, 64, 0, stream>>>(flagp);
    detect_kernel<<<256, 256, 0, stream>>>(x, in_sizes[0], flagp);

    // ---- folded-bias init + weight cache (gain/bias folded) ----
    bias_init_kernel<<<8, 256, 0, stream>>>(bias_qkv, bias_ffn1, ffn1_b1,
                                            bias_pw1, bias_ffn2, ffn2_b1, flagp);
    WTab tab;
    tab.w[0] = ffn1_w1; tab.wt[0] = w_ffn1_1; tab.g[0] = ln1_g; tab.bs[0] = ln1_b; tab.bd[0] = bias_ffn1; tab.K[0] = 512;  tab.N[0] = 2048;
    tab.w[1] = ffn1_w2; tab.wt[1] = w_ffn1_2; tab.g[1] = nullptr; tab.bs[1] = nullptr; tab.bd[1] = nullptr; tab.K[1] = 2048; tab.N[1] = 512;
    tab.w[2] = wq; tab.wt[2] = w_qkv;                tab.g[2] = lnq_g; tab.bs[2] = lnq_b; tab.bd[2] = bias_qkv;        tab.K[2] = 512; tab.N[2] = 512;
    tab.w[3] = wk; tab.wt[3] = w_qkv + 262144;       tab.g[3] = lnk_g; tab.bs[3] = lnk_b; tab.bd[3] = bias_qkv + 512;  tab.K[3] = 512; tab.N[3] = 512;
    tab.w[4] = wv; tab.wt[4] = w_qkv + 524288;       tab.g[4] = lnv_g; tab.bs[4] = lnv_b; tab.bd[4] = bias_qkv + 1024; tab.K[4] = 512; tab.N[4] = 512;
    tab.w[5] = wpos; tab.wt[5] = w_pos; tab.g[5] = nullptr; tab.bs[5] = nullptr; tab.bd[5] = nullptr; tab.K[5] = 512; tab.N[5] = 512;
    tab.w[6] = wfc;  tab.wt[6] = w_fc;  tab.g[6] = nullptr; tab.bs[6] = nullptr; tab.bd[6] = nullptr; tab.K[6] = 512; tab.N[6] = 512;
    tab.w[7] = pw1;  tab.wt[7] = w_pw1; tab.g[7] = cln_g; tab.bs[7] = cln_b; tab.bd[7] = bias_pw1; tab.K[7] = 512; tab.N[7] = 2048;
    tab.w[8] = pw2;  tab.wt[8] = w_pw2; tab.g[8] = nullptr; tab.bs[8] = nullptr; tab.bd[8] = nullptr; tab.K[8] = 1024; tab.N[8] = 512;
    tab.w[9] = ffn2_w1; tab.wt[9] = w_ffn2_1; tab.g[9] = ln2_g; tab.bs[9] = ln2_b; tab.bd[9] = bias_ffn2; tab.K[9] = 512; tab.N[9] = 2048;
    tab.w[10] = ffn2_w2; tab.wt[10] = w_ffn2_2; tab.g[10] = nullptr; tab.bs[10] = nullptr; tab.bd[10] = nullptr; tab.K[10] = 2048; tab.N[10] = 512;
    wtrans_all<<<dim3(64, 64, 11), 256, 0, stream>>>(tab, flagp);

    // ---- P = pos_emb @ wpos ----
    cvt_bf_kernel<<<2048, 256, 0, stream>>>(pos_emb, tmpb, 524288, flagp);
    launch_gemm(tmpb, w_pos, nullptr, nullptr, nullptr, pb, 1024, 512, 512, 1.0f, 0, 1, flagp, stream);

    // ---- FFN1 half-step (ln1 gain/bias folded into w1/bias_ffn1) ----
    ln_kernel<512, 1, 0, false, true, false><<<BT, 256, 0, stream>>>(x, nullptr, nullptr, tmpb, act, flagp);
    launch_gemm(tmpb, w_ffn1_1, bias_ffn1, nullptr, nullptr, hbf, BT, 2048, 512, 1.0f, 1, 1, flagp, stream);
    launch_gemm(hbf, w_ffn1_2, nullptr, ffn1_b2, act, act, BT, 512, 2048, 0.5f, 0, 0, flagp, stream);

    // ---- merged QKV projection (one xhat LN, gains folded per-slice) ----
    ln_kernel<512, 0, 0, false, false, false><<<BT, 256, 0, stream>>>(act, nullptr, nullptr, tmpb, nullptr, flagp);
    launch_gemm(tmpb, w_qkv, bias_qkv, nullptr, nullptr, qkvb, BT, 1536, 512, 1.0f, 0, 1, flagp, stream);

    // ---- attention prep ----
    add_qbias_kernel<<<16384, 256, 0, stream>>>(qkvb, pbu, pbv, qu, qv, flagp);
    vtrans_kernel<<<dim3(32, 16, 8), 256, 0, stream>>>(qkvb + 1024, vt);

    // ---- attention, 2 batches per pass ----
    for (int b0 = 0; b0 < 8; b0 += 2) {
        const bf16u* qu_b = qu + (size_t)b0 * 524288;
        const bf16u* qv_b = qv + (size_t)b0 * 524288;
        const bf16u* k_b  = qkvb + (size_t)b0 * 1572864 + 512;
        const bf16u* vt_b = vt + (size_t)b0 * 524288;
        bf16u* ob_b = obb + (size_t)b0 * 524288;
        attn_score_mfma<<<dim3(8, 8, 32), 256, 0, stream>>>(qu_b, qv_b, k_b, pb, S, BD);
        attn_softmax_kernel<<<dim3(1024, 8, 2), 256, 0, stream>>>(S, BD);
        attn_pv_mfma<<<dim3(16, 8, 2), 256, 0, stream>>>(S, vt_b, ob_b);
    }
    launch_gemm(obb, w_fc, nullptr, nullptr, act, act, BT, 512, 512, 1.0f, 0, 0, flagp, stream);

    // ---- convolution module (cln folded into pw1/bias_pw1) ----
    ln_kernel<512, 0, 0, false, false, false><<<BT, 256, 0, stream>>>(act, nullptr, nullptr, tmpb, nullptr, flagp);
    launch_gemm(tmpb, w_pw1, bias_pw1, nullptr, nullptr, hbf, BT, 2048, 512, 1.0f, 0, 1, flagp, stream);
    glu_kernel<<<32768, 256, 0, stream>>>(hbf, Gbf, 8388608);
    dwconv_kernel<<<2048, 256, 0, stream>>>(Gbf, dw_w, DWbf, flagp);
    ln_kernel<1024, 2, 0, true, false, true><<<BT, 256, 0, stream>>>(DWbf, bn_g, bn_b, LObf, nullptr, flagp);
    launch_gemm(LObf, w_pw2, nullptr, nullptr, act, act, BT, 512, 1024, 1.0f, 0, 0, flagp, stream);

    // ---- FFN2 half-step (ln2 folded) ----
    ln_kernel<512, 0, 0, false, false, false><<<BT, 256, 0, stream>>>(act, nullptr, nullptr, tmpb, nullptr, flagp);
    launch_gemm(tmpb, w_ffn2_1, bias_ffn2, nullptr, nullptr, hbf, BT, 2048, 512, 1.0f, 1, 1, flagp, stream);
    launch_gemm(hbf, w_ffn2_2, nullptr, ffn2_b2, act, act, BT, 512, 2048, 0.5f, 0, 0, flagp, stream);

    // ---- final LN -> d_out ----
    ln_kernel<512, 0, 1, false, false, true><<<BT, 256, 0, stream>>>(act, lnf_g, lnf_b, d_out, nullptr, flagp);
}